// Round 1
// baseline (607.159 us; speedup 1.0000x reference)
//
#include <hip/hip_runtime.h>
#include <math.h>

#define DMODEL 512
#define NSEQ 2048
#define NHEAD 8
#define DK 64
#define DV 64
#define MFEAT 266
#define MP 272          // padded feature dim (zero tail)
#define NT 32           // number of chunks (chunk = 64)
#define LN_EPS 1e-6f
#define KERNEL_EPS 1e-4f
#define NORM_STAB 1e-6f

// ---------------- LayerNorm on q ----------------
__global__ __launch_bounds__(256) void ln_kernel(const float* __restrict__ q,
                                                 const float* __restrict__ gamma,
                                                 const float* __restrict__ beta,
                                                 float* __restrict__ qn) {
    int row = blockIdx.x;
    int tid = threadIdx.x;
    const float* x = q + (size_t)row * DMODEL;
    float x0 = x[tid], x1 = x[tid + 256];
    float s = x0 + x1, ss = x0 * x0 + x1 * x1;
    for (int o = 32; o > 0; o >>= 1) {
        s += __shfl_down(s, o);
        ss += __shfl_down(ss, o);
    }
    __shared__ float sbuf[4], ssbuf[4];
    __shared__ float mu_s, rstd_s;
    int wid = tid >> 6, lane = tid & 63;
    if (lane == 0) { sbuf[wid] = s; ssbuf[wid] = ss; }
    __syncthreads();
    if (tid == 0) {
        float st = sbuf[0] + sbuf[1] + sbuf[2] + sbuf[3];
        float sst = ssbuf[0] + ssbuf[1] + ssbuf[2] + ssbuf[3];
        float mu = st / (float)DMODEL;
        float var = sst / (float)DMODEL - mu * mu;
        mu_s = mu;
        rstd_s = rsqrtf(var + LN_EPS);
    }
    __syncthreads();
    float mu = mu_s, rstd = rstd_s;
    qn[(size_t)row * DMODEL + tid] = (x0 - mu) * rstd * gamma[tid] + beta[tid];
    qn[(size_t)row * DMODEL + tid + 256] = (x1 - mu) * rstd * gamma[tid + 256] + beta[tid + 256];
}

// ---------------- generic fp32 tiled GEMM: C = scale*(A@B) [+bias][+residual] ----------------
// A [Mr,Kr], B [Kr,Nr], C [Mr,Nr], all row-major. Mr%64==0, Nr%64==0, Kr%16==0.
__global__ __launch_bounds__(256) void gemm_kernel(const float* __restrict__ A,
                                                   const float* __restrict__ B,
                                                   float* __restrict__ C,
                                                   int Mr, int Nr, int Kr, float scale,
                                                   const float* __restrict__ bias,
                                                   const float* __restrict__ residual) {
    __shared__ float As[16][65];  // [k][row]
    __shared__ float Bs[16][65];  // [k][col]
    int bm = blockIdx.y * 64, bn = blockIdx.x * 64;
    int tid = threadIdx.x;
    int tx = tid & 15, ty = tid >> 4;
    float acc[4][4] = {};
    for (int k0 = 0; k0 < Kr; k0 += 16) {
        for (int l = 0; l < 4; ++l) {
            int idx = tid + l * 256;
            int r = idx >> 4, kk = idx & 15;
            As[kk][r] = A[(size_t)(bm + r) * Kr + k0 + kk];
        }
        for (int l = 0; l < 4; ++l) {
            int idx = tid + l * 256;
            int kk = idx >> 6, c = idx & 63;
            Bs[kk][c] = B[(size_t)(k0 + kk) * Nr + bn + c];
        }
        __syncthreads();
        for (int kk = 0; kk < 16; ++kk) {
            float a[4], b[4];
            for (int r = 0; r < 4; ++r) a[r] = As[kk][ty * 4 + r];
            for (int c = 0; c < 4; ++c) b[c] = Bs[kk][tx * 4 + c];
            for (int r = 0; r < 4; ++r)
                for (int c = 0; c < 4; ++c) acc[r][c] += a[r] * b[c];
        }
        __syncthreads();
    }
    for (int r = 0; r < 4; ++r) {
        int row = bm + ty * 4 + r;
        for (int c = 0; c < 4; ++c) {
            int col = bn + tx * 4 + c;
            float v = acc[r][c] * scale;
            if (bias) v += bias[col];
            if (residual) v += residual[(size_t)row * Nr + col];
            C[(size_t)row * Nr + col] = v;
        }
    }
}

// ---------------- h_k + global max partials ----------------
__global__ __launch_bounds__(256) void hk_kernel(const float* __restrict__ kh,
                                                 float* __restrict__ hk,
                                                 float* __restrict__ partial) {
    int idx = blockIdx.x * 256 + threadIdx.x;  // 0..16383
    int n = idx >> 3, h = idx & 7;
    const float* row = kh + (size_t)n * DMODEL + h * DK;
    float s = 0.f;
    for (int d = 0; d < DK; ++d) { float v = row[d]; s += v * v; }
    float hv = -0.5f * s;
    hk[(size_t)h * NSEQ + n] = hv;
    float m = hv;
    for (int o = 32; o > 0; o >>= 1) m = fmaxf(m, __shfl_down(m, o));
    __shared__ float wmax[4];
    if ((threadIdx.x & 63) == 0) wmax[threadIdx.x >> 6] = m;
    __syncthreads();
    if (threadIdx.x == 0)
        partial[blockIdx.x] = fmaxf(fmaxf(wmax[0], wmax[1]), fmaxf(wmax[2], wmax[3]));
}

__global__ void maxreduce_kernel(const float* __restrict__ partial, float* __restrict__ kstab) {
    float m = partial[threadIdx.x];  // 64 threads
    for (int o = 32; o > 0; o >>= 1) m = fmaxf(m, __shfl_down(m, o));
    if (threadIdx.x == 0) kstab[0] = m;
}

// ---------------- random feature maps: qp / kp (padded to MP, zero tail) ----------------
__global__ __launch_bounds__(256) void feat_kernel(const float* __restrict__ xh,
                                                   const float* __restrict__ rf,
                                                   const float* __restrict__ hk,
                                                   const float* __restrict__ kstab,
                                                   float* __restrict__ outp, int isQ) {
    int nt = blockIdx.x;  // 0..31 (64-row tile)
    int h = blockIdx.y;   // 0..7
    int tid = threadIdx.x;
    __shared__ float xs[64][65];
    __shared__ float rs[64][65];
    for (int l = 0; l < 16; ++l) {
        int idx = tid + l * 256;
        int r = idx >> 6, dd = idx & 63;
        xs[r][dd] = xh[(size_t)(nt * 64 + r) * DMODEL + h * DK + dd];
    }
    float ks = kstab[0];
    const float cnorm = 0.06131393394849658f;  // 266^-0.5
    int mloc = tid & 63, tgroup = tid >> 6;
    for (int mt = 0; mt < 5; ++mt) {
        __syncthreads();
        for (int l = 0; l < 16; ++l) {
            int idx = tid + l * 256;
            int mr = idx >> 6, dd = idx & 63;
            int m = mt * 64 + mr;
            rs[mr][dd] = (m < MFEAT) ? rf[(size_t)m * DK + dd] : 0.f;
        }
        __syncthreads();
        int m = mt * 64 + mloc;
        for (int jj = 0; jj < 16; ++jj) {
            int nloc = jj * 4 + tgroup;
            float acc = 0.f;
            for (int d = 0; d < 64; ++d) acc += xs[nloc][d] * rs[mloc][d];
            if (m < MP) {
                int n = nt * 64 + nloc;
                float val;
                if (m < MFEAT) {
                    if (isQ) val = cnorm * (expf(acc) + KERNEL_EPS);
                    else val = cnorm * (expf(hk[(size_t)h * NSEQ + n] + acc - ks) + KERNEL_EPS);
                } else {
                    val = 0.f;  // zero pad so dots over MP are exact
                }
                outp[((size_t)h * NSEQ + n) * MP + m] = val;
            }
        }
    }
}

// ---------------- phase A: per-chunk sums KV[m][dv], Ks[m] ----------------
__global__ __launch_bounds__(256) void chunksum_kernel(const float* __restrict__ kp,
                                                       const float* __restrict__ vh,
                                                       float* __restrict__ KV,
                                                       float* __restrict__ Ks) {
    int mt = blockIdx.x;  // 0..4
    int t = blockIdx.y;   // 0..31
    int h = blockIdx.z;   // 0..7
    int tid = threadIdx.x;
    int tx = tid & 15, ty = tid >> 4;
    __shared__ float kps[64][65];  // [i][mloc]
    __shared__ float vs[64][65];   // [i][dv]
    for (int l = 0; l < 16; ++l) {
        int idx = tid + l * 256;
        int i = idx >> 6, mm = idx & 63;
        int m = mt * 64 + mm;
        kps[i][mm] = (m < MP) ? kp[((size_t)h * NSEQ + t * 64 + i) * MP + m] : 0.f;
        vs[i][mm] = vh[(size_t)(t * 64 + i) * DMODEL + h * DV + mm];
    }
    __syncthreads();
    float acc[4][4] = {};
    for (int i = 0; i < 64; ++i) {
        float a[4], b[4];
        for (int r = 0; r < 4; ++r) a[r] = kps[i][ty * 4 + r];
        for (int c = 0; c < 4; ++c) b[c] = vs[i][tx * 4 + c];
        for (int r = 0; r < 4; ++r)
            for (int c = 0; c < 4; ++c) acc[r][c] += a[r] * b[c];
    }
    for (int r = 0; r < 4; ++r) {
        int m = mt * 64 + ty * 4 + r;
        if (m < MP) {
            for (int c = 0; c < 4; ++c)
                KV[(((size_t)h * NT + t) * MP + m) * DV + tx * 4 + c] = acc[r][c];
        }
    }
    if (tid < 64) {
        int m = mt * 64 + tid;
        if (m < MP) {
            float s = 0.f;
            for (int i = 0; i < 64; ++i) s += kps[i][tid];
            Ks[((size_t)h * NT + t) * MP + m] = s;
        }
    }
}

// ---------------- exclusive prefix over chunks (in place) ----------------
__global__ void scankv_kernel(float* __restrict__ KV) {
    int idx = blockIdx.x * 256 + threadIdx.x;
    if (idx >= NHEAD * MP * DV) return;
    int h = idx / (MP * DV);
    int rem = idx % (MP * DV);
    size_t base = (size_t)h * NT * MP * DV + rem;
    float run = 0.f;
    for (int t = 0; t < NT; ++t) {
        size_t o = base + (size_t)t * MP * DV;
        float v = KV[o];
        KV[o] = run;
        run += v;
    }
}

__global__ void scanks_kernel(float* __restrict__ Ks, float* __restrict__ Ktot) {
    int idx = blockIdx.x * 256 + threadIdx.x;
    if (idx >= NHEAD * MP) return;
    int h = idx / MP, m = idx % MP;
    size_t base = (size_t)h * NT * MP + m;
    float run = 0.f;
    for (int t = 0; t < NT; ++t) {
        size_t o = base + (size_t)t * MP;
        float v = Ks[o];
        Ks[o] = run;
        run += v;
    }
    Ktot[(size_t)h * MP + m] = run;
}

// ---------------- phase C: intra-chunk causal + inter-chunk state ----------------
__global__ __launch_bounds__(256) void phasec_kernel(const float* __restrict__ qp,
                                                     const float* __restrict__ kp,
                                                     const float* __restrict__ vh,
                                                     const float* __restrict__ KV,
                                                     const float* __restrict__ Ks,
                                                     const float* __restrict__ Ktot,
                                                     float* __restrict__ attn) {
    int t = blockIdx.x, h = blockIdx.y;
    int tid = threadIdx.x;
    int tx = tid & 15, ty = tid >> 4;
    __shared__ float buf0[64][65];
    __shared__ float buf1[64][65];
    __shared__ float rowsum_s[64];
    __shared__ float fscale_s[64];
    const float* qpb = qp + ((size_t)h * NSEQ + t * 64) * MP;
    const float* kpb = kp + ((size_t)h * NSEQ + t * 64) * MP;

    // A[i][j] = qp_i . kp_j over padded features
    float accA[4][4] = {};
    for (int mt = 0; mt < 5; ++mt) {
        __syncthreads();
        for (int l = 0; l < 16; ++l) {
            int idx = tid + l * 256;
            int r = idx >> 6, mm = idx & 63;
            int m = mt * 64 + mm;
            buf0[r][mm] = (m < MP) ? qpb[(size_t)r * MP + m] : 0.f;
            buf1[r][mm] = (m < MP) ? kpb[(size_t)r * MP + m] : 0.f;
        }
        __syncthreads();
        for (int d = 0; d < 64; ++d) {
            float a[4], b[4];
            for (int r = 0; r < 4; ++r) a[r] = buf0[ty * 4 + r][d];
            for (int c = 0; c < 4; ++c) b[c] = buf1[tx * 4 + c][d];
            for (int r = 0; r < 4; ++r)
                for (int c = 0; c < 4; ++c) accA[r][c] += a[r] * b[c];
        }
    }
    __syncthreads();
    for (int r = 0; r < 4; ++r)
        for (int c = 0; c < 4; ++c) buf0[ty * 4 + r][tx * 4 + c] = accA[r][c];
    __syncthreads();
    // masked row sums (j <= i), and stage V
    if (tid < 64) {
        float s = 0.f;
        for (int j = 0; j <= tid; ++j) s += buf0[tid][j];
        rowsum_s[tid] = s;
    }
    for (int l = 0; l < 16; ++l) {
        int idx = tid + l * 256;
        int i = idx >> 6, dv = idx & 63;
        buf1[i][dv] = vh[(size_t)(t * 64 + i) * DMODEL + h * DV + dv];
    }
    __syncthreads();
    // intra: (A masked) @ V
    float accO[4][4] = {};
    for (int j = 0; j < 64; ++j) {
        float b[4];
        for (int c = 0; c < 4; ++c) b[c] = buf1[j][tx * 4 + c];
        for (int r = 0; r < 4; ++r) {
            int i = ty * 4 + r;
            float a = (j <= i) ? buf0[i][j] : 0.f;
            for (int c = 0; c < 4; ++c) accO[r][c] += a * b[c];
        }
    }
    __syncthreads();
    // inter: qp @ S_prev
    const float* Sp = KV + ((size_t)h * NT + t) * MP * DV;
    for (int mt = 0; mt < 5; ++mt) {
        for (int l = 0; l < 16; ++l) {
            int idx = tid + l * 256;
            int r = idx >> 6, mm = idx & 63;
            int mq = mt * 64 + mm;   // qp feature col
            int ms = mt * 64 + r;    // S feature row
            buf0[r][mm] = (mq < MP) ? qpb[(size_t)r * MP + mq] : 0.f;
            buf1[r][mm] = (ms < MP) ? Sp[(size_t)ms * DV + mm] : 0.f;
        }
        __syncthreads();
        for (int d = 0; d < 64; ++d) {
            float a[4], b[4];
            for (int r = 0; r < 4; ++r) a[r] = buf0[ty * 4 + r][d];
            for (int c = 0; c < 4; ++c) b[c] = buf1[d][tx * 4 + c];
            for (int r = 0; r < 4; ++r)
                for (int c = 0; c < 4; ++c) accO[r][c] += a[r] * b[c];
        }
        __syncthreads();
    }
    // denominators
    if (tid < 64) {
        int i = tid;
        const float* qrow = qpb + (size_t)i * MP;
        const float* sprev = Ks + ((size_t)h * NT + t) * MP;
        const float* kt = Ktot + (size_t)h * MP;
        float dc = rowsum_s[i], df = 0.f;
        for (int m = 0; m < MFEAT; ++m) {
            float qv = qrow[m];
            dc += qv * sprev[m];
            df += qv * kt[m];
        }
        float dst = df;
        if (fabsf(dst) <= NORM_STAB) dst += 2.f * NORM_STAB;
        fscale_s[i] = (1.f / dc) / dst;
    }
    __syncthreads();
    for (int r = 0; r < 4; ++r) {
        int i = ty * 4 + r;
        float fs = fscale_s[i];
        int n = t * 64 + i;
        for (int c = 0; c < 4; ++c)
            attn[(size_t)n * DMODEL + h * DV + tx * 4 + c] = accO[r][c] * fs;
    }
}

extern "C" void kernel_launch(void* const* d_in, const int* in_sizes, int n_in,
                              void* d_out, int out_size, void* d_ws, size_t ws_size,
                              hipStream_t stream) {
    const float* q = (const float*)d_in[0];
    const float* k = (const float*)d_in[1];
    const float* v = (const float*)d_in[2];
    const float* Wq = (const float*)d_in[3];
    const float* Wk = (const float*)d_in[4];
    const float* Wv = (const float*)d_in[5];
    const float* Wfc = (const float*)d_in[6];
    const float* bfc = (const float*)d_in[7];
    const float* gamma = (const float*)d_in[8];
    const float* beta = (const float*)d_in[9];
    const float* rf = (const float*)d_in[10];
    float* out = (float*)d_out;

    float* ws = (float*)d_ws;
    float* qn = ws;                                      // 2048*512 (reused as attn out)
    float* qh = qn + (size_t)NSEQ * DMODEL;              // 2048*512
    float* kh = qh + (size_t)NSEQ * DMODEL;              // 2048*512
    float* vhb = kh + (size_t)NSEQ * DMODEL;             // 2048*512
    float* qp = vhb + (size_t)NSEQ * DMODEL;             // 8*2048*272
    float* kp = qp + (size_t)NHEAD * NSEQ * MP;          // 8*2048*272
    float* KV = kp + (size_t)NHEAD * NSEQ * MP;          // 8*32*272*64
    float* Ks = KV + (size_t)NHEAD * NT * MP * DV;       // 8*32*272
    float* Ktot = Ks + (size_t)NHEAD * NT * MP;          // 8*272
    float* hk = Ktot + (size_t)NHEAD * MP;               // 8*2048
    float* partial = hk + (size_t)NHEAD * NSEQ;          // 64
    float* kstab = partial + 64;                         // 1

    const float scale = 0.21022410381342863f;  // 512^-0.25

    ln_kernel<<<NSEQ, 256, 0, stream>>>(q, gamma, beta, qn);
    dim3 g(DMODEL / 64, NSEQ / 64);
    gemm_kernel<<<g, 256, 0, stream>>>(qn, Wq, qh, NSEQ, DMODEL, DMODEL, scale, nullptr, nullptr);
    gemm_kernel<<<g, 256, 0, stream>>>(k, Wk, kh, NSEQ, DMODEL, DMODEL, scale, nullptr, nullptr);
    gemm_kernel<<<g, 256, 0, stream>>>(v, Wv, vhb, NSEQ, DMODEL, DMODEL, 1.f, nullptr, nullptr);
    hk_kernel<<<64, 256, 0, stream>>>(kh, hk, partial);
    maxreduce_kernel<<<1, 64, 0, stream>>>(partial, kstab);
    dim3 gf(NSEQ / 64, NHEAD);
    feat_kernel<<<gf, 256, 0, stream>>>(qh, rf, hk, kstab, qp, 1);
    feat_kernel<<<gf, 256, 0, stream>>>(kh, rf, hk, kstab, kp, 0);
    dim3 ga(5, NT, NHEAD);
    chunksum_kernel<<<ga, 256, 0, stream>>>(kp, vhb, KV, Ks);
    scankv_kernel<<<(NHEAD * MP * DV + 255) / 256, 256, 0, stream>>>(KV);
    scanks_kernel<<<(NHEAD * MP + 255) / 256, 256, 0, stream>>>(Ks, Ktot);
    dim3 gc(NT, NHEAD);
    phasec_kernel<<<gc, 256, 0, stream>>>(qp, kp, vhb, KV, Ks, Ktot, qn);
    gemm_kernel<<<g, 256, 0, stream>>>(qn, Wfc, out, NSEQ, DMODEL, DMODEL, 1.f, bfc, q);
}